// Round 2
// baseline (11073.705 us; speedup 1.0000x reference)
//
#include <hip/hip_runtime.h>
#include <hip/hip_fp16.h>

#define N_NODES 500000
#define N_EDGES 1000000
#define N_GRAPHS 20000

__global__ __launch_bounds__(256) void fill_f32(float* p, float v, int n) {
  int i = blockIdx.x * 256 + threadIdx.x;
  if (i < n) p[i] = v;
}

__global__ __launch_bounds__(256) void deg_accum(const int* __restrict__ dst, float* deg, int e) {
  int i = blockIdx.x * 256 + threadIdx.x;
  if (i < e) atomicAdd(&deg[dst[i]], 1.0f);
}

__global__ __launch_bounds__(256) void rsqrt_inplace(float* p, int n) {
  int i = blockIdx.x * 256 + threadIdx.x;
  if (i < n) p[i] = rsqrtf(p[i]);
}

__global__ __launch_bounds__(256) void cnt_accum(const int* __restrict__ batch, float* cnt, int n) {
  int i = blockIdx.x * 256 + threadIdx.x;
  if (i < n) atomicAdd(&cnt[batch[i]], 1.0f);
}

__global__ __launch_bounds__(256) void inv_inplace(float* p, int n) {
  int i = blockIdx.x * 256 + threadIdx.x;
  if (i < n) p[i] = 1.0f / fmaxf(p[i], 1.0f);
}

__device__ inline float ldval(const float* p) { return *p; }
__device__ inline float ldval(const __half* p) { return __half2float(*p); }

// out[M,Nout] = f(in[M,K]) @ W[:, coff:coff+Nout] (+ epilogue)
// IN_MODE:  0 identity; 2 v*rs[row]
// OUT_MODE: 0 v*rs[row] -> fp16 out (ld=Nout) AND fp32 out2 (ld=Nout)
//           1 relu(v+bo[oc]) -> fp32 out; 2 v+bo[oc] -> fp32 out
template <typename TIN, int IN_MODE, int OUT_MODE>
__global__ __launch_bounds__(256) void gemm_k(
    const TIN* __restrict__ in, const float* __restrict__ W,
    void* __restrict__ outp, float* __restrict__ out2,
    const float* __restrict__ rs, const float* __restrict__ bo,
    int M, int K, int Nout, int ldw, int coff) {
  constexpr int BM = 128, BN = 80, BK = 16;
  __shared__ float As[BK][BM + 4];
  __shared__ float Bs[BK][BN + 4];
  const int tid = threadIdx.x;
  const int tx = tid & 15, ty = tid >> 4;
  const int row0 = blockIdx.y * BM;
  const int col0 = blockIdx.x * BN;
  float acc[8][5];
#pragma unroll
  for (int i = 0; i < 8; ++i)
#pragma unroll
    for (int j = 0; j < 5; ++j) acc[i][j] = 0.f;

  for (int k0 = 0; k0 < K; k0 += BK) {
#pragma unroll
    for (int i = 0; i < 8; ++i) {
      int idx = tid + i * 256;            // 2048 = BM*BK
      int r = idx >> 4, c = idx & 15;
      int gr = row0 + r, gk = k0 + c;
      float v = 0.f;
      if (gr < M && gk < K) {
        v = ldval(&in[(size_t)gr * K + gk]);
        if (IN_MODE == 2) v *= rs[gr];
      }
      As[c][r] = v;
    }
#pragma unroll
    for (int i = 0; i < 5; ++i) {
      int idx = tid + i * 256;            // 1280 = BK*BN
      int r = idx / BN, c = idx - r * BN;
      int gk = k0 + r, oc = col0 + c;
      Bs[r][c] = (gk < K && oc < Nout) ? W[(size_t)gk * ldw + coff + oc] : 0.f;
    }
    __syncthreads();
#pragma unroll
    for (int kk = 0; kk < BK; ++kk) {
      float a[8], b[5];
#pragma unroll
      for (int i = 0; i < 8; ++i) a[i] = As[kk][ty * 8 + i];
#pragma unroll
      for (int j = 0; j < 5; ++j) b[j] = Bs[kk][tx * 5 + j];
#pragma unroll
      for (int i = 0; i < 8; ++i)
#pragma unroll
        for (int j = 0; j < 5; ++j) acc[i][j] = fmaf(a[i], b[j], acc[i][j]);
    }
    __syncthreads();
  }

#pragma unroll
  for (int i = 0; i < 8; ++i) {
    int gr = row0 + ty * 8 + i;
    if (gr >= M) continue;
    float sc = (OUT_MODE == 0) ? rs[gr] : 1.f;
#pragma unroll
    for (int j = 0; j < 5; ++j) {
      int oc = col0 + tx * 5 + j;
      if (oc >= Nout) continue;
      float v = acc[i][j];
      if (OUT_MODE == 0) {
        v *= sc;
        ((__half*)outp)[(size_t)gr * Nout + oc] = __float2half(v);
        out2[(size_t)gr * Nout + oc] = v;
      } else if (OUT_MODE == 1) {
        ((float*)outp)[(size_t)gr * Nout + oc] = fmaxf(v + bo[oc], 0.f);
      } else {
        ((float*)outp)[(size_t)gr * Nout + oc] = v + bo[oc];
      }
    }
  }
}

// agg[dst, :] += hs[src, :]  (78-wide, fp16 src, fp32 atomics)
__global__ __launch_bounds__(256) void scatter78(
    const __half* __restrict__ hs, float* __restrict__ agg,
    const int* __restrict__ src, const int* __restrict__ dst) {
  unsigned idx = blockIdx.x * 256u + threadIdx.x;
  if (idx >= (unsigned)N_EDGES * 39u) return;
  unsigned e = idx / 39u, c = idx - e * 39u;
  int s = src[e], d = dst[e];
  __half2 v = *reinterpret_cast<const __half2*>(hs + (size_t)s * 78 + 2 * c);
  float* o = agg + (size_t)d * 78 + 2 * c;
  atomicAdd(o, __half2float(v.x));
  atomicAdd(o + 1, __half2float(v.y));
}

// dsth[n, coff+k] = fp16(relu(dinv[n]*aggc[n,k] + b[coff+k]))
__global__ __launch_bounds__(256) void transform78(
    const float* __restrict__ aggc, const float* __restrict__ dinv,
    const float* __restrict__ b, __half* __restrict__ dsth, int ld, int coff) {
  unsigned idx = blockIdx.x * 256u + threadIdx.x;
  if (idx >= (unsigned)N_NODES * 39u) return;
  unsigned n = idx / 39u, c = idx - n * 39u;
  float di = dinv[n];
  float2 v = *reinterpret_cast<const float2*>(aggc + (size_t)n * 78 + 2 * c);
  float r0 = fmaxf(fmaf(di, v.x, b[coff + 2 * c]), 0.f);
  float r1 = fmaxf(fmaf(di, v.y, b[coff + 2 * c + 1]), 0.f);
  __half2 h;
  h.x = __float2half(r0);
  h.y = __float2half(r1);
  *reinterpret_cast<__half2*>(dsth + (size_t)n * ld + coff + 2 * c) = h;
}

// gsum[batch[n], coff+k] += relu(dinv[n]*aggc[n,k] + b3[coff+k])
__global__ __launch_bounds__(256) void pool78(
    const float* __restrict__ aggc, const float* __restrict__ dinv,
    const float* __restrict__ b3, const int* __restrict__ batch,
    float* __restrict__ gsum, int coff) {
  unsigned idx = blockIdx.x * 256u + threadIdx.x;
  if (idx >= (unsigned)N_NODES * 39u) return;
  unsigned n = idx / 39u, c = idx - n * 39u;
  int g = batch[n];
  float di = dinv[n];
  float2 v = *reinterpret_cast<const float2*>(aggc + (size_t)n * 78 + 2 * c);
  float r0 = fmaxf(fmaf(di, v.x, b3[coff + 2 * c]), 0.f);
  float r1 = fmaxf(fmaf(di, v.y, b3[coff + 2 * c + 1]), 0.f);
  float* o = gsum + (size_t)g * 312 + coff + 2 * c;
  atomicAdd(o, r0);
  atomicAdd(o + 1, r1);
}

extern "C" void kernel_launch(void* const* d_in, const int* in_sizes, int n_in,
                              void* d_out, int out_size, void* d_ws, size_t ws_size,
                              hipStream_t stream) {
  const float* x   = (const float*)d_in[0];
  const int* ei    = (const int*)d_in[1];
  const int* batch = (const int*)d_in[2];
  const float* W1 = (const float*)d_in[3];
  const float* b1 = (const float*)d_in[4];
  const float* W2 = (const float*)d_in[5];
  const float* b2 = (const float*)d_in[6];
  const float* W3 = (const float*)d_in[7];
  const float* b3 = (const float*)d_in[8];
  const float* fW1 = (const float*)d_in[9];
  const float* fb1 = (const float*)d_in[10];
  const float* fW2 = (const float*)d_in[11];
  const float* fb2 = (const float*)d_in[12];
  float* out = (float*)d_out;

  const int Nn = N_NODES, E = N_EDGES, G = N_GRAPHS;
  const int* src = ei;
  const int* dst = ei + E;

  // ---- compact workspace layout (~470 MB) ----
  float* AGGC   = (float*)d_ws;                          // [N,78] f32 (scatter target)
  __half* HSh   = (__half*)(AGGC + (size_t)Nn * 78);     // [N,78] f16 (hs chunk)
  __half* AGG1h = HSh + (size_t)Nn * 78;                 // [N,78] f16 (L2 input)
  __half* AGG2h = AGG1h + (size_t)Nn * 78;               // [N,156] f16 (L3 input)
  float* dinv   = (float*)(AGG2h + (size_t)Nn * 156);    // [N] f32
  // overlays (stream-ordered, regions dead by then):
  float* gsum = (float*)AGG1h;                           // [G,312] f32 (after L2 GEMMs done)
  float* gcnt = gsum + (size_t)G * 312;                  // [G]
  float* fc1  = AGGC;                                    // [G,1024] f32 (after last pool)

  dim3 blk(256);
  const int gN39 = (int)(((unsigned)Nn * 39u + 255u) / 256u);   // 76172
  const int gE39 = (int)(((unsigned)E * 39u + 255u) / 256u);    // 152344
  const dim3 gemmNodeGrid(1, (Nn + 127) / 128);

  // ---- dinv = rsqrt(1 + dst-degree) ----
  fill_f32<<<(Nn + 255) / 256, blk, 0, stream>>>(dinv, 1.0f, Nn);
  deg_accum<<<(E + 255) / 256, blk, 0, stream>>>(dst, dinv, E);
  rsqrt_inplace<<<(Nn + 255) / 256, blk, 0, stream>>>(dinv, Nn);

  // ---- layer 1 ----
  gemm_k<float, 0, 0><<<gemmNodeGrid, blk, 0, stream>>>(
      x, W1, HSh, AGGC, dinv, nullptr, Nn, 78, 78, 78, 0);
  scatter78<<<gE39, blk, 0, stream>>>(HSh, AGGC, src, dst);
  transform78<<<gN39, blk, 0, stream>>>(AGGC, dinv, b1, AGG1h, 78, 0);

  // ---- layer 2 (2 chunks of 78 output features) ----
  for (int c = 0; c < 2; ++c) {
    gemm_k<__half, 0, 0><<<gemmNodeGrid, blk, 0, stream>>>(
        AGG1h, W2, HSh, AGGC, dinv, nullptr, Nn, 78, 78, 156, 78 * c);
    scatter78<<<gE39, blk, 0, stream>>>(HSh, AGGC, src, dst);
    transform78<<<gN39, blk, 0, stream>>>(AGGC, dinv, b2, AGG2h, 156, 78 * c);
  }

  // ---- pool setup (AGG1h region is now free -> gsum/gcnt) ----
  fill_f32<<<((G * 312) + 255) / 256, blk, 0, stream>>>(gsum, 0.f, G * 312);
  fill_f32<<<(G + 255) / 256, blk, 0, stream>>>(gcnt, 0.f, G);
  cnt_accum<<<(Nn + 255) / 256, blk, 0, stream>>>(batch, gcnt, Nn);
  inv_inplace<<<(G + 255) / 256, blk, 0, stream>>>(gcnt, G);

  // ---- layer 3 (4 chunks of 78) + fused pool ----
  for (int c = 0; c < 4; ++c) {
    gemm_k<__half, 0, 0><<<gemmNodeGrid, blk, 0, stream>>>(
        AGG2h, W3, HSh, AGGC, dinv, nullptr, Nn, 156, 78, 312, 78 * c);
    scatter78<<<gE39, blk, 0, stream>>>(HSh, AGGC, src, dst);
    pool78<<<gN39, blk, 0, stream>>>(AGGC, dinv, b3, batch, gsum, 78 * c);
  }

  // ---- FC1: relu((gsum*ginv) @ fW1 + fb1) -> fc1 (overlays AGGC) ----
  {
    dim3 g((1024 + 79) / 80, (G + 127) / 128);
    gemm_k<float, 2, 1><<<g, blk, 0, stream>>>(
        gsum, fW1, fc1, nullptr, gcnt, fb1, G, 312, 1024, 1024, 0);
  }
  // ---- FC2: out = fc1 @ fW2 + fb2 ----
  {
    dim3 g((128 + 79) / 80, (G + 127) / 128);
    gemm_k<float, 0, 2><<<g, blk, 0, stream>>>(
        fc1, fW2, out, nullptr, nullptr, fb2, G, 1024, 128, 128, 0);
  }
}

// Round 3
// 8086.457 us; speedup vs baseline: 1.3694x; 1.3694x over previous
//
#include <hip/hip_runtime.h>
#include <hip/hip_fp16.h>

#define N_NODES 500000
#define N_EDGES 1000000
#define N_GRAPHS 20000

typedef _Float16 f16x8 __attribute__((ext_vector_type(8)));
typedef float f32x4 __attribute__((ext_vector_type(4)));

__global__ __launch_bounds__(256) void fill_f32(float* p, float v, int n) {
  int i = blockIdx.x * 256 + threadIdx.x;
  if (i < n) p[i] = v;
}

__global__ __launch_bounds__(256) void deg_accum(const int* __restrict__ dst, float* deg, int e) {
  int i = blockIdx.x * 256 + threadIdx.x;
  if (i < e) atomicAdd(&deg[dst[i]], 1.0f);
}

__global__ __launch_bounds__(256) void rsqrt_inplace(float* p, int n) {
  int i = blockIdx.x * 256 + threadIdx.x;
  if (i < n) p[i] = rsqrtf(p[i]);
}

__global__ __launch_bounds__(256) void cnt_accum(const int* __restrict__ batch, float* cnt, int n) {
  int i = blockIdx.x * 256 + threadIdx.x;
  if (i < n) atomicAdd(&cnt[batch[i]], 1.0f);
}

__global__ __launch_bounds__(256) void inv_inplace(float* p, int n) {
  int i = blockIdx.x * 256 + threadIdx.x;
  if (i < n) p[i] = 1.0f / fmaxf(p[i], 1.0f);
}

// zero npad u32 words per row at [r*stride + off .. +npad)
__global__ __launch_bounds__(256) void pad_zero_u32(unsigned* p, int stride, int off, int npad, int rows) {
  int i = blockIdx.x * 256 + threadIdx.x;
  if (i >= rows * npad) return;
  int r = i / npad, j = i - r * npad;
  p[(size_t)r * stride + off + j] = 0u;
}

// MFMA GEMM: out[M, Nout] = f16(in[M, K(pad KP)]) @ f16(W[:, coff+col0 .. ]) + epilogue
// Block tile 128x80, 4 waves each 32x80, K-step 32 (v_mfma_f32_16x16x32_f16).
// OUT_MODE 0: v*=rs[row]; write f16 outp (stride LDO) AND f32 out2 (stride 78)
// OUT_MODE 1: relu(v+bo[oc]) -> f16 outp ; OUT_MODE 2: v+bo[oc] -> f32 outp
template <typename TIN, int OUT_MODE>
__global__ __launch_bounds__(256) void gemm_mfma(
    const TIN* __restrict__ in, const float* __restrict__ W,
    void* __restrict__ outp, float* __restrict__ out2,
    const float* __restrict__ rs, const float* __restrict__ bo,
    int M, int K, int KP, int Nout, int ldw, int coff, int LDO) {
  __shared__ _Float16 As[128][40];  // 32 k + 8 pad
  __shared__ _Float16 Bs[80][40];   // Bs[col][k], 32 k + 8 pad
  const int tid = threadIdx.x;
  const int lane = tid & 63;
  const int wid = tid >> 6;
  const int row0 = blockIdx.y * 128;
  const int col0 = blockIdx.x * 80;
  const f32x4 z4 = {0.f, 0.f, 0.f, 0.f};
  f32x4 acc[2][5];
#pragma unroll
  for (int a = 0; a < 2; ++a)
#pragma unroll
    for (int b = 0; b < 5; ++b) acc[a][b] = z4;

  const int nsteps = (K + 31) >> 5;
  for (int s = 0; s < nsteps; ++s) {
    const int k0 = s << 5;
    if constexpr (sizeof(TIN) == 2) {  // fp16 input, 16B chunks
#pragma unroll
      for (int i = 0; i < 2; ++i) {
        int id = tid + i * 256;            // 512 chunks = 128 rows x 4
        int r = id >> 2, kc = (id & 3) << 3;
        int gr = row0 + r, gk = k0 + kc;
        uint4 v = {0u, 0u, 0u, 0u};
        if (gr < M && gk + 8 <= KP)
          v = *reinterpret_cast<const uint4*>((const _Float16*)in + (size_t)gr * KP + gk);
        *reinterpret_cast<uint4*>(&As[r][kc]) = v;
      }
    } else {  // fp32 input (layer 1: x, stride 78 floats), float2 loads
#pragma unroll
      for (int i = 0; i < 8; ++i) {
        int id = tid + i * 256;            // 2048 = 128 rows x 16 float2
        int r = id >> 4, c2 = id & 15;
        int gr = row0 + r, gk = k0 + 2 * c2;
        __half2 h = __floats2half2_rn(0.f, 0.f);
        if (gr < M && gk + 2 <= KP) {
          float2 v = *reinterpret_cast<const float2*>((const float*)in + (size_t)gr * KP + gk);
          h = __floats2half2_rn(v.x, v.y);
        }
        *reinterpret_cast<__half2*>(&As[r][2 * c2]) = h;
      }
    }
    // B stage: Bs[col][k] = f16(W[k0+k][coff+col0+col]), 2560 elems
#pragma unroll
    for (int i = 0; i < 10; ++i) {
      int id = tid + i * 256;
      int k = id / 80, c = id - k * 80;
      float v = 0.f;
      if (k0 + k < K && col0 + c < Nout)
        v = W[(size_t)(k0 + k) * ldw + coff + col0 + c];
      Bs[c][k] = (_Float16)v;
    }
    __syncthreads();
    f16x8 af[2], bf[5];
#pragma unroll
    for (int rf = 0; rf < 2; ++rf)
      af[rf] = *reinterpret_cast<const f16x8*>(&As[wid * 32 + rf * 16 + (lane & 15)][(lane >> 4) * 8]);
#pragma unroll
    for (int nf = 0; nf < 5; ++nf)
      bf[nf] = *reinterpret_cast<const f16x8*>(&Bs[nf * 16 + (lane & 15)][(lane >> 4) * 8]);
#pragma unroll
    for (int rf = 0; rf < 2; ++rf)
#pragma unroll
      for (int nf = 0; nf < 5; ++nf)
        acc[rf][nf] = __builtin_amdgcn_mfma_f32_16x16x32_f16(af[rf], bf[nf], acc[rf][nf], 0, 0, 0);
    __syncthreads();
  }

  // epilogue: C/D layout col=lane&15, row=(lane>>4)*4+reg
#pragma unroll
  for (int rf = 0; rf < 2; ++rf) {
#pragma unroll
    for (int j = 0; j < 4; ++j) {
      int gr = row0 + wid * 32 + rf * 16 + (lane >> 4) * 4 + j;
      if (gr >= M) continue;
      float sc = (OUT_MODE == 0) ? rs[gr] : 0.f;
#pragma unroll
      for (int nf = 0; nf < 5; ++nf) {
        int oc = col0 + nf * 16 + (lane & 15);
        if (oc >= Nout) continue;
        float v = acc[rf][nf][j];
        if (OUT_MODE == 0) {
          v *= sc;
          ((_Float16*)outp)[(size_t)gr * LDO + oc] = (_Float16)v;
          out2[(size_t)gr * 78 + oc] = v;
        } else if (OUT_MODE == 1) {
          ((_Float16*)outp)[(size_t)gr * LDO + oc] = (_Float16)fmaxf(v + bo[oc], 0.f);
        } else {
          ((float*)outp)[(size_t)gr * LDO + oc] = v + bo[oc];
        }
      }
    }
  }
}

// agg[dst, :] += hs[src, :]  (78-wide, fp16 src stride 78, fp32 atomics)
__global__ __launch_bounds__(256) void scatter78(
    const __half* __restrict__ hs, float* __restrict__ agg,
    const int* __restrict__ src, const int* __restrict__ dst) {
  unsigned idx = blockIdx.x * 256u + threadIdx.x;
  if (idx >= (unsigned)N_EDGES * 39u) return;
  unsigned e = idx / 39u, c = idx - e * 39u;
  int s = src[e], d = dst[e];
  __half2 v = *reinterpret_cast<const __half2*>(hs + (size_t)s * 78 + 2 * c);
  float* o = agg + (size_t)d * 78 + 2 * c;
  atomicAdd(o, __half2float(v.x));
  atomicAdd(o + 1, __half2float(v.y));
}

// dsth[n, coff+k] = fp16(relu(dinv[n]*aggc[n,k] + b[coff+k]))
__global__ __launch_bounds__(256) void transform78(
    const float* __restrict__ aggc, const float* __restrict__ dinv,
    const float* __restrict__ b, __half* __restrict__ dsth, int ld, int coff) {
  unsigned idx = blockIdx.x * 256u + threadIdx.x;
  if (idx >= (unsigned)N_NODES * 39u) return;
  unsigned n = idx / 39u, c = idx - n * 39u;
  float di = dinv[n];
  float2 v = *reinterpret_cast<const float2*>(aggc + (size_t)n * 78 + 2 * c);
  float r0 = fmaxf(fmaf(di, v.x, b[coff + 2 * c]), 0.f);
  float r1 = fmaxf(fmaf(di, v.y, b[coff + 2 * c + 1]), 0.f);
  *reinterpret_cast<__half2*>(dsth + (size_t)n * ld + coff + 2 * c) = __floats2half2_rn(r0, r1);
}

// gsum[batch[n], coff+k] += relu(dinv[n]*aggc[n,k] + b3[coff+k])
__global__ __launch_bounds__(256) void pool78(
    const float* __restrict__ aggc, const float* __restrict__ dinv,
    const float* __restrict__ b3, const int* __restrict__ batch,
    float* __restrict__ gsum, int coff) {
  unsigned idx = blockIdx.x * 256u + threadIdx.x;
  if (idx >= (unsigned)N_NODES * 39u) return;
  unsigned n = idx / 39u, c = idx - n * 39u;
  int g = batch[n];
  float di = dinv[n];
  float2 v = *reinterpret_cast<const float2*>(aggc + (size_t)n * 78 + 2 * c);
  float r0 = fmaxf(fmaf(di, v.x, b3[coff + 2 * c]), 0.f);
  float r1 = fmaxf(fmaf(di, v.y, b3[coff + 2 * c + 1]), 0.f);
  float* o = gsum + (size_t)g * 312 + coff + 2 * c;
  atomicAdd(o, r0);
  atomicAdd(o + 1, r1);
}

// GA[g, 0:320] = fp16(gsum[g, 0:312] * ginv[g]), pad zeros
__global__ __launch_bounds__(256) void ga_convert(
    const float* __restrict__ gsum, const float* __restrict__ ginv,
    _Float16* __restrict__ GA) {
  int i = blockIdx.x * 256 + threadIdx.x;
  if (i >= N_GRAPHS * 160) return;
  int g = i / 160, c = i - g * 160;
  __half2 h = __floats2half2_rn(0.f, 0.f);
  if (c < 156) {
    float gi = ginv[g];
    float2 v = *reinterpret_cast<const float2*>(gsum + (size_t)g * 312 + 2 * c);
    h = __floats2half2_rn(v.x * gi, v.y * gi);
  }
  *reinterpret_cast<__half2*>(GA + (size_t)g * 320 + 2 * c) = h;
}

extern "C" void kernel_launch(void* const* d_in, const int* in_sizes, int n_in,
                              void* d_out, int out_size, void* d_ws, size_t ws_size,
                              hipStream_t stream) {
  const float* x   = (const float*)d_in[0];
  const int* ei    = (const int*)d_in[1];
  const int* batch = (const int*)d_in[2];
  const float* W1 = (const float*)d_in[3];
  const float* b1 = (const float*)d_in[4];
  const float* W2 = (const float*)d_in[5];
  const float* b2 = (const float*)d_in[6];
  const float* W3 = (const float*)d_in[7];
  const float* b3 = (const float*)d_in[8];
  const float* fW1 = (const float*)d_in[9];
  const float* fb1 = (const float*)d_in[10];
  const float* fW2 = (const float*)d_in[11];
  const float* fb2 = (const float*)d_in[12];
  float* out = (float*)d_out;

  const int Nn = N_NODES, E = N_EDGES, G = N_GRAPHS;
  const int* src = ei;
  const int* dst = ei + E;

  // ---- workspace layout (~476 MB) ----
  float* AGGC      = (float*)d_ws;                        // [N,78]  f32 scatter target
  _Float16* HSh    = (_Float16*)(AGGC + (size_t)Nn * 78); // [N,78]  f16 hs chunk
  _Float16* AGG1h  = HSh + (size_t)Nn * 78;               // [N,80]  f16 L2 input (KP=80)
  _Float16* AGG2h  = AGG1h + (size_t)Nn * 80;             // [N,160] f16 L3 input (KP=160)
  float* dinv      = (float*)(AGG2h + (size_t)Nn * 160);  // [N]
  // overlays (stream-ordered; regions dead by first write):
  float* gsum   = (float*)AGG1h;                          // [G,312] after L2 gemms
  float* gcnt   = gsum + (size_t)G * 312;                 // [G]
  _Float16* GA  = HSh;                                    // [G,320] after last scatter
  _Float16* fc1 = (_Float16*)AGGC;                        // [G,1024] after last pool

  dim3 blk(256);
  const int gN39 = (int)(((unsigned)Nn * 39u + 255u) / 256u);
  const int gE39 = (int)(((unsigned)E * 39u + 255u) / 256u);
  const dim3 nodeGrid(1, (Nn + 127) / 128);  // 3907

  // zero pad columns (ws is 0xAA-poisoned once)
  pad_zero_u32<<<(Nn + 255) / 256, blk, 0, stream>>>((unsigned*)AGG1h, 40, 39, 1, Nn);
  pad_zero_u32<<<(2 * Nn + 255) / 256, blk, 0, stream>>>((unsigned*)AGG2h, 80, 78, 2, Nn);

  // dinv = rsqrt(1 + dst-degree)
  fill_f32<<<(Nn + 255) / 256, blk, 0, stream>>>(dinv, 1.0f, Nn);
  deg_accum<<<(E + 255) / 256, blk, 0, stream>>>(dst, dinv, E);
  rsqrt_inplace<<<(Nn + 255) / 256, blk, 0, stream>>>(dinv, Nn);

  // ---- layer 1: hs1 = (x@W1)*dinv ----
  gemm_mfma<float, 0><<<nodeGrid, blk, 0, stream>>>(
      x, W1, HSh, AGGC, dinv, nullptr, Nn, 78, 78, 78, 78, 0, 78);
  scatter78<<<gE39, blk, 0, stream>>>((const __half*)HSh, AGGC, src, dst);
  transform78<<<gN39, blk, 0, stream>>>(AGGC, dinv, b1, (__half*)AGG1h, 80, 0);

  // ---- layer 2 (2 chunks of 78) ----
  for (int c = 0; c < 2; ++c) {
    gemm_mfma<_Float16, 0><<<nodeGrid, blk, 0, stream>>>(
        AGG1h, W2, HSh, AGGC, dinv, nullptr, Nn, 78, 80, 78, 156, 78 * c, 78);
    scatter78<<<gE39, blk, 0, stream>>>((const __half*)HSh, AGGC, src, dst);
    transform78<<<gN39, blk, 0, stream>>>(AGGC, dinv, b2, (__half*)AGG2h, 160, 78 * c);
  }

  // ---- pool setup (AGG1h region now free -> gsum/gcnt) ----
  fill_f32<<<((G * 312) + 255) / 256, blk, 0, stream>>>(gsum, 0.f, G * 312);
  fill_f32<<<(G + 255) / 256, blk, 0, stream>>>(gcnt, 0.f, G);
  cnt_accum<<<(Nn + 255) / 256, blk, 0, stream>>>(batch, gcnt, Nn);
  inv_inplace<<<(G + 255) / 256, blk, 0, stream>>>(gcnt, G);

  // ---- layer 3 (4 chunks of 78) + fused pool ----
  for (int c = 0; c < 4; ++c) {
    gemm_mfma<_Float16, 0><<<nodeGrid, blk, 0, stream>>>(
        AGG2h, W3, HSh, AGGC, dinv, nullptr, Nn, 156, 160, 78, 312, 78 * c, 78);
    scatter78<<<gE39, blk, 0, stream>>>((const __half*)HSh, AGGC, src, dst);
    pool78<<<gN39, blk, 0, stream>>>(AGGC, dinv, b3, batch, gsum, 78 * c);
  }

  // ---- mean-pool scale -> fp16 GA (overlays HSh) ----
  ga_convert<<<(G * 160 + 255) / 256, blk, 0, stream>>>(gsum, gcnt, GA);

  // ---- FC1: relu(GA @ fW1 + fb1) -> fc1 f16 (overlays AGGC) ----
  {
    dim3 g((1024 + 79) / 80, (G + 127) / 128);
    gemm_mfma<_Float16, 1><<<g, blk, 0, stream>>>(
        GA, fW1, fc1, nullptr, nullptr, fb1, G, 312, 320, 1024, 1024, 0, 1024);
  }
  // ---- FC2: out = fc1 @ fW2 + fb2 ----
  {
    dim3 g((128 + 79) / 80, (G + 127) / 128);
    gemm_mfma<_Float16, 2><<<g, blk, 0, stream>>>(
        fc1, fW2, out, nullptr, nullptr, fb2, G, 1024, 1024, 128, 128, 0, 128);
  }
}

// Round 4
// 3886.371 us; speedup vs baseline: 2.8494x; 2.0807x over previous
//
#include <hip/hip_runtime.h>
#include <hip/hip_fp16.h>

#define N_NODES 500000
#define N_EDGES 1000000
#define N_GRAPHS 20000

typedef _Float16 f16x8 __attribute__((ext_vector_type(8)));
typedef float f32x4 __attribute__((ext_vector_type(4)));

__global__ __launch_bounds__(256) void fill_f32(float* p, float v, int n) {
  int i = blockIdx.x * 256 + threadIdx.x;
  if (i < n) p[i] = v;
}

__global__ __launch_bounds__(256) void fill_u32(unsigned* p, unsigned v, int n) {
  int i = blockIdx.x * 256 + threadIdx.x;
  if (i < n) p[i] = v;
}

__global__ __launch_bounds__(256) void hist_dst(const int* __restrict__ dst, int* cnt, int e) {
  int i = blockIdx.x * 256 + threadIdx.x;
  if (i < e) atomicAdd(&cnt[dst[i]], 1);
}

__global__ __launch_bounds__(256) void cnt_accum(const int* __restrict__ batch, float* cnt, int n) {
  int i = blockIdx.x * 256 + threadIdx.x;
  if (i < n) atomicAdd(&cnt[batch[i]], 1.0f);
}

__global__ __launch_bounds__(256) void inv_inplace(float* p, int n) {
  int i = blockIdx.x * 256 + threadIdx.x;
  if (i < n) p[i] = 1.0f / fmaxf(p[i], 1.0f);
}

// zero npad u32 words per row at [r*stride + off .. +npad)
__global__ __launch_bounds__(256) void pad_zero_u32(unsigned* p, int stride, int off, int npad, int rows) {
  int i = blockIdx.x * 256 + threadIdx.x;
  if (i >= rows * npad) return;
  int r = i / npad, j = i - r * npad;
  p[(size_t)r * stride + off + j] = 0u;
}

// ---- 2-level exclusive scan over deg[N] (1024 elems/block) ----
__global__ __launch_bounds__(256) void scanA(const int* __restrict__ deg, int* __restrict__ loc,
                                             int* __restrict__ partials, int n) {
  __shared__ int ts[256];
  int b = blockIdx.x, t = threadIdx.x;
  int base = b * 1024 + t * 4;
  int v[4], s = 0;
#pragma unroll
  for (int j = 0; j < 4; ++j) {
    v[j] = (base + j < n) ? deg[base + j] : 0;
    s += v[j];
  }
  ts[t] = s;
  __syncthreads();
  for (int off = 1; off < 256; off <<= 1) {
    int x = (t >= off) ? ts[t - off] : 0;
    __syncthreads();
    ts[t] += x;
    __syncthreads();
  }
  if (t == 255) partials[b] = ts[255];
  int run = ts[t] - s;  // exclusive
#pragma unroll
  for (int j = 0; j < 4; ++j) {
    if (base + j < n) loc[base + j] = run;
    run += v[j];
  }
}

__global__ __launch_bounds__(512) void scanB(int* partials, int nb) {
  __shared__ int s[512];
  int t = threadIdx.x;
  s[t] = (t < nb) ? partials[t] : 0;
  __syncthreads();
  if (t == 0) {
    int run = 0;
    for (int i = 0; i < nb; ++i) { int v = s[i]; s[i] = run; run += v; }
  }
  __syncthreads();
  if (t < nb) partials[t] = s[t];
}

// rowptr final = loc + partials[blk]; also copy to cursor, set rowptr[n]=E
__global__ __launch_bounds__(256) void scanC(int* __restrict__ rowptr, const int* __restrict__ partials,
                                             int* __restrict__ cur, int n, int e) {
  int i = blockIdx.x * 256 + threadIdx.x;
  if (i < n) {
    int v = rowptr[i] + partials[i >> 10];
    rowptr[i] = v;
    cur[i] = v;
  }
  if (i == 0) rowptr[n] = e;
}

__global__ __launch_bounds__(256) void dinv_k(const int* __restrict__ rowptr, float* dinv, int n) {
  int i = blockIdx.x * 256 + threadIdx.x;
  if (i < n) dinv[i] = rsqrtf(1.0f + (float)(rowptr[i + 1] - rowptr[i]));
}

__global__ __launch_bounds__(256) void bucket(const int* __restrict__ src, const int* __restrict__ dst,
                                              int* __restrict__ cur, int* __restrict__ ssrc, int e) {
  int i = blockIdx.x * 256 + threadIdx.x;
  if (i < e) ssrc[atomicAdd(&cur[dst[i]], 1)] = src[i];
}

// MFMA GEMM: out[M, Nout] = f16(in[M, K(pad KP)]) @ f16(W[:, coff..]) + epilogue
// OUT_MODE 0: v*=rs[row] -> f16 outp (stride LDO)
// OUT_MODE 1: relu(v+bo[oc]) -> f16 outp ; OUT_MODE 2: v+bo[oc] -> f32 outp
template <typename TIN, int OUT_MODE>
__global__ __launch_bounds__(256) void gemm_mfma(
    const TIN* __restrict__ in, const float* __restrict__ W,
    void* __restrict__ outp, const float* __restrict__ rs, const float* __restrict__ bo,
    int M, int K, int KP, int Nout, int ldw, int coff, int LDO) {
  __shared__ _Float16 As[128][40];
  __shared__ _Float16 Bs[80][40];
  const int tid = threadIdx.x;
  const int lane = tid & 63;
  const int wid = tid >> 6;
  const int row0 = blockIdx.y * 128;
  const int col0 = blockIdx.x * 80;
  const f32x4 z4 = {0.f, 0.f, 0.f, 0.f};
  f32x4 acc[2][5];
#pragma unroll
  for (int a = 0; a < 2; ++a)
#pragma unroll
    for (int b = 0; b < 5; ++b) acc[a][b] = z4;

  const int nsteps = (K + 31) >> 5;
  for (int s = 0; s < nsteps; ++s) {
    const int k0 = s << 5;
    if constexpr (sizeof(TIN) == 2) {
#pragma unroll
      for (int i = 0; i < 2; ++i) {
        int id = tid + i * 256;
        int r = id >> 2, kc = (id & 3) << 3;
        int gr = row0 + r, gk = k0 + kc;
        uint4 v = {0u, 0u, 0u, 0u};
        if (gr < M && gk + 8 <= KP)
          v = *reinterpret_cast<const uint4*>((const _Float16*)in + (size_t)gr * KP + gk);
        *reinterpret_cast<uint4*>(&As[r][kc]) = v;
      }
    } else {
#pragma unroll
      for (int i = 0; i < 8; ++i) {
        int id = tid + i * 256;
        int r = id >> 4, c2 = id & 15;
        int gr = row0 + r, gk = k0 + 2 * c2;
        __half2 h = __floats2half2_rn(0.f, 0.f);
        if (gr < M && gk + 2 <= KP) {
          float2 v = *reinterpret_cast<const float2*>((const float*)in + (size_t)gr * KP + gk);
          h = __floats2half2_rn(v.x, v.y);
        }
        *reinterpret_cast<__half2*>(&As[r][2 * c2]) = h;
      }
    }
#pragma unroll
    for (int i = 0; i < 10; ++i) {
      int id = tid + i * 256;
      int k = id / 80, c = id - k * 80;
      float v = 0.f;
      if (k0 + k < K && col0 + c < Nout)
        v = W[(size_t)(k0 + k) * ldw + coff + col0 + c];
      Bs[c][k] = (_Float16)v;
    }
    __syncthreads();
    f16x8 af[2], bf[5];
#pragma unroll
    for (int rf = 0; rf < 2; ++rf)
      af[rf] = *reinterpret_cast<const f16x8*>(&As[wid * 32 + rf * 16 + (lane & 15)][(lane >> 4) * 8]);
#pragma unroll
    for (int nf = 0; nf < 5; ++nf)
      bf[nf] = *reinterpret_cast<const f16x8*>(&Bs[nf * 16 + (lane & 15)][(lane >> 4) * 8]);
#pragma unroll
    for (int rf = 0; rf < 2; ++rf)
#pragma unroll
      for (int nf = 0; nf < 5; ++nf)
        acc[rf][nf] = __builtin_amdgcn_mfma_f32_16x16x32_f16(af[rf], bf[nf], acc[rf][nf], 0, 0, 0);
    __syncthreads();
  }

#pragma unroll
  for (int rf = 0; rf < 2; ++rf) {
#pragma unroll
    for (int j = 0; j < 4; ++j) {
      int gr = row0 + wid * 32 + rf * 16 + (lane >> 4) * 4 + j;
      if (gr >= M) continue;
      float sc = (OUT_MODE == 0) ? rs[gr] : 0.f;
#pragma unroll
      for (int nf = 0; nf < 5; ++nf) {
        int oc = col0 + nf * 16 + (lane & 15);
        if (oc >= Nout) continue;
        float v = acc[rf][nf][j];
        if (OUT_MODE == 0) {
          ((_Float16*)outp)[(size_t)gr * LDO + oc] = (_Float16)(v * sc);
        } else if (OUT_MODE == 1) {
          ((_Float16*)outp)[(size_t)gr * LDO + oc] = (_Float16)fmaxf(v + bo[oc], 0.f);
        } else {
          ((float*)outp)[(size_t)gr * LDO + oc] = v + bo[oc];
        }
      }
    }
  }
}

// Fused segment-sum + transform. hs stride 80 fp16.
// acc = hs[n] + sum_{e in seg(n)} hs[ssrc[e]];  r = relu(dinv[n]*acc + b[coff+c])
// MODE 0: write fp16 dsth[n*ldo + coff + c]
// MODE 1: atomicAdd gsum[batch[n]*312 + coff + c]
template <int MODE>
__global__ __launch_bounds__(256) void aggregate78(
    const _Float16* __restrict__ hs, const int* __restrict__ rowptr,
    const int* __restrict__ ssrc, const float* __restrict__ dinv,
    const float* __restrict__ b, _Float16* __restrict__ dsth, int ldo, int coff,
    const int* __restrict__ batch, float* __restrict__ gsum) {
  unsigned idx = blockIdx.x * 256u + threadIdx.x;
  if (idx >= (unsigned)N_NODES * 39u) return;
  unsigned n = idx / 39u, c = idx - n * 39u;
  const unsigned co = 2u * c;
  __half2 h0 = *reinterpret_cast<const __half2*>(hs + (size_t)n * 80 + co);
  float ax = __half2float(h0.x), ay = __half2float(h0.y);
  int s0 = rowptr[n], s1 = rowptr[n + 1];
  for (int i = s0; i < s1; ++i) {
    int s = ssrc[i];
    __half2 v = *reinterpret_cast<const __half2*>(hs + (size_t)s * 80 + co);
    ax += __half2float(v.x);
    ay += __half2float(v.y);
  }
  float di = dinv[n];
  float r0 = fmaxf(fmaf(di, ax, b[coff + co]), 0.f);
  float r1 = fmaxf(fmaf(di, ay, b[coff + co + 1]), 0.f);
  if (MODE == 0) {
    *reinterpret_cast<__half2*>(dsth + (size_t)n * ldo + coff + co) = __floats2half2_rn(r0, r1);
  } else {
    float* o = gsum + (size_t)batch[n] * 312 + coff + co;
    atomicAdd(o, r0);
    atomicAdd(o + 1, r1);
  }
}

// GA[g, 0:320] = fp16(gsum[g, 0:312] * ginv[g]), pad zeros
__global__ __launch_bounds__(256) void ga_convert(
    const float* __restrict__ gsum, const float* __restrict__ ginv,
    _Float16* __restrict__ GA) {
  int i = blockIdx.x * 256 + threadIdx.x;
  if (i >= N_GRAPHS * 160) return;
  int g = i / 160, c = i - g * 160;
  __half2 h = __floats2half2_rn(0.f, 0.f);
  if (c < 156) {
    float gi = ginv[g];
    float2 v = *reinterpret_cast<const float2*>(gsum + (size_t)g * 312 + 2 * c);
    h = __floats2half2_rn(v.x * gi, v.y * gi);
  }
  *reinterpret_cast<__half2*>(GA + (size_t)g * 320 + 2 * c) = h;
}

extern "C" void kernel_launch(void* const* d_in, const int* in_sizes, int n_in,
                              void* d_out, int out_size, void* d_ws, size_t ws_size,
                              hipStream_t stream) {
  const float* x   = (const float*)d_in[0];
  const int* ei    = (const int*)d_in[1];
  const int* batch = (const int*)d_in[2];
  const float* W1 = (const float*)d_in[3];
  const float* b1 = (const float*)d_in[4];
  const float* W2 = (const float*)d_in[5];
  const float* b2 = (const float*)d_in[6];
  const float* W3 = (const float*)d_in[7];
  const float* b3 = (const float*)d_in[8];
  const float* fW1 = (const float*)d_in[9];
  const float* fb1 = (const float*)d_in[10];
  const float* fW2 = (const float*)d_in[11];
  const float* fb2 = (const float*)d_in[12];
  float* out = (float*)d_out;

  const int Nn = N_NODES, E = N_EDGES, G = N_GRAPHS;
  const int* src = ei;
  const int* dst = ei + E;

  // ---- workspace layout (~410 MB) ----
  _Float16* HSh   = (_Float16*)d_ws;                      // [N,80]  hs chunk
  _Float16* AGG1h = HSh + (size_t)Nn * 80;                // [N,80]  L2 input
  _Float16* AGG2h = AGG1h + (size_t)Nn * 80;              // [N,160] L3 input
  float* dinv     = (float*)(AGG2h + (size_t)Nn * 160);   // [N]
  int* rowptr     = (int*)(dinv + Nn);                    // [N+1]
  int* cur        = rowptr + Nn + 1;                      // [N]
  int* ssrc       = cur + Nn;                             // [E]
  int* partials   = ssrc + E;                             // [512]
  float* gsum     = (float*)(partials + 512);             // [G,312]
  float* gcnt     = gsum + (size_t)G * 312;               // [G]
  _Float16* GA    = (_Float16*)(gcnt + G);                // [G,320]
  _Float16* fc1   = GA + (size_t)G * 320;                 // [G,1024]

  dim3 blk(256);
  const int gN39 = (int)(((unsigned)Nn * 39u + 255u) / 256u);
  const dim3 nodeGrid(1, (Nn + 127) / 128);
  const int NB = (Nn + 1023) / 1024;  // 489

  // ---- CSR build (dst-sorted src list) ----
  fill_u32<<<(Nn + 255) / 256, blk, 0, stream>>>((unsigned*)cur, 0u, Nn);
  hist_dst<<<(E + 255) / 256, blk, 0, stream>>>(dst, cur, E);
  scanA<<<NB, blk, 0, stream>>>(cur, rowptr, partials, Nn);
  scanB<<<1, 512, 0, stream>>>(partials, NB);
  scanC<<<(Nn + 255) / 256, blk, 0, stream>>>(rowptr, partials, cur, Nn, E);
  dinv_k<<<(Nn + 255) / 256, blk, 0, stream>>>(rowptr, dinv, Nn);
  bucket<<<(E + 255) / 256, blk, 0, stream>>>(src, dst, cur, ssrc, E);

  // ---- zero fp16 pad columns (ws poisoned 0xAA once) ----
  pad_zero_u32<<<(Nn + 255) / 256, blk, 0, stream>>>((unsigned*)HSh, 40, 39, 1, Nn);
  pad_zero_u32<<<(Nn + 255) / 256, blk, 0, stream>>>((unsigned*)AGG1h, 40, 39, 1, Nn);
  pad_zero_u32<<<(2 * Nn + 255) / 256, blk, 0, stream>>>((unsigned*)AGG2h, 80, 78, 2, Nn);

  // ---- pool denominators ----
  fill_f32<<<((G * 312) + 255) / 256, blk, 0, stream>>>(gsum, 0.f, G * 312);
  fill_f32<<<(G + 255) / 256, blk, 0, stream>>>(gcnt, 0.f, G);
  cnt_accum<<<(Nn + 255) / 256, blk, 0, stream>>>(batch, gcnt, Nn);
  inv_inplace<<<(G + 255) / 256, blk, 0, stream>>>(gcnt, G);

  // ---- layer 1 ----
  gemm_mfma<float, 0><<<nodeGrid, blk, 0, stream>>>(
      x, W1, HSh, dinv, nullptr, Nn, 78, 78, 78, 78, 0, 80);
  aggregate78<0><<<gN39, blk, 0, stream>>>(HSh, rowptr, ssrc, dinv, b1, AGG1h, 80, 0, nullptr, nullptr);

  // ---- layer 2 (2 chunks of 78) ----
  for (int c = 0; c < 2; ++c) {
    gemm_mfma<_Float16, 0><<<nodeGrid, blk, 0, stream>>>(
        AGG1h, W2, HSh, dinv, nullptr, Nn, 78, 80, 78, 156, 78 * c, 80);
    aggregate78<0><<<gN39, blk, 0, stream>>>(HSh, rowptr, ssrc, dinv, b2, AGG2h, 160, 78 * c, nullptr, nullptr);
  }

  // ---- layer 3 (4 chunks of 78) + fused pool ----
  for (int c = 0; c < 4; ++c) {
    gemm_mfma<_Float16, 0><<<nodeGrid, blk, 0, stream>>>(
        AGG2h, W3, HSh, dinv, nullptr, Nn, 156, 160, 78, 312, 78 * c, 80);
    aggregate78<1><<<gN39, blk, 0, stream>>>(HSh, rowptr, ssrc, dinv, b3, nullptr, 0, 78 * c, batch, gsum);
  }

  // ---- mean-pool scale -> fp16 GA ----
  ga_convert<<<(G * 160 + 255) / 256, blk, 0, stream>>>(gsum, gcnt, GA);

  // ---- FC1: relu(GA @ fW1 + fb1) -> fc1 f16 ----
  {
    dim3 g((1024 + 79) / 80, (G + 127) / 128);
    gemm_mfma<_Float16, 1><<<g, blk, 0, stream>>>(
        GA, fW1, fc1, nullptr, fb1, G, 312, 320, 1024, 1024, 0, 1024);
  }
  // ---- FC2: out = fc1 @ fW2 + fb2 ----
  {
    dim3 g((128 + 79) / 80, (G + 127) / 128);
    gemm_mfma<_Float16, 2><<<g, blk, 0, stream>>>(
        fc1, fW2, out, nullptr, fb2, G, 1024, 1024, 128, 128, 0, 128);
  }
}

// Round 5
// 2267.279 us; speedup vs baseline: 4.8841x; 1.7141x over previous
//
#include <hip/hip_runtime.h>
#include <hip/hip_fp16.h>

#define N_NODES 500000
#define N_EDGES 1000000
#define N_GRAPHS 20000

typedef _Float16 f16x8 __attribute__((ext_vector_type(8)));
typedef float f32x4 __attribute__((ext_vector_type(4)));

__global__ __launch_bounds__(256) void fill_u32(unsigned* p, unsigned v, int n) {
  int i = blockIdx.x * 256 + threadIdx.x;
  if (i < n) p[i] = v;
}

__global__ __launch_bounds__(256) void hist_dst(const int* __restrict__ dst, int* cnt, int e) {
  int i = blockIdx.x * 256 + threadIdx.x;
  if (i < e) atomicAdd(&cnt[dst[i]], 1);
}

// zero npad u32 words per row at [r*stride + off .. +npad)
__global__ __launch_bounds__(256) void pad_zero_u32(unsigned* p, int stride, int off, int npad, int rows) {
  int i = blockIdx.x * 256 + threadIdx.x;
  if (i >= rows * npad) return;
  int r = i / npad, j = i - r * npad;
  p[(size_t)r * stride + off + j] = 0u;
}

// ---- 2-level exclusive scan over deg[N] (1024 elems/block) ----
__global__ __launch_bounds__(256) void scanA(const int* __restrict__ deg, int* __restrict__ loc,
                                             int* __restrict__ partials, int n) {
  __shared__ int ts[256];
  int b = blockIdx.x, t = threadIdx.x;
  int base = b * 1024 + t * 4;
  int v[4], s = 0;
#pragma unroll
  for (int j = 0; j < 4; ++j) {
    v[j] = (base + j < n) ? deg[base + j] : 0;
    s += v[j];
  }
  ts[t] = s;
  __syncthreads();
  for (int off = 1; off < 256; off <<= 1) {
    int x = (t >= off) ? ts[t - off] : 0;
    __syncthreads();
    ts[t] += x;
    __syncthreads();
  }
  if (t == 255) partials[b] = ts[255];
  int run = ts[t] - s;  // exclusive
#pragma unroll
  for (int j = 0; j < 4; ++j) {
    if (base + j < n) loc[base + j] = run;
    run += v[j];
  }
}

__global__ __launch_bounds__(512) void scanB(int* partials, int nb) {
  __shared__ int s[512];
  int t = threadIdx.x;
  s[t] = (t < nb) ? partials[t] : 0;
  __syncthreads();
  if (t == 0) {
    int run = 0;
    for (int i = 0; i < nb; ++i) { int v = s[i]; s[i] = run; run += v; }
  }
  __syncthreads();
  if (t < nb) partials[t] = s[t];
}

__global__ __launch_bounds__(256) void scanC(int* __restrict__ rowptr, const int* __restrict__ partials,
                                             int* __restrict__ cur, int n, int e) {
  int i = blockIdx.x * 256 + threadIdx.x;
  if (i < n) {
    int v = rowptr[i] + partials[i >> 10];
    rowptr[i] = v;
    cur[i] = v;
  }
  if (i == 0) rowptr[n] = e;
}

__global__ __launch_bounds__(256) void dinv_k(const int* __restrict__ rowptr, float* dinv, int n) {
  int i = blockIdx.x * 256 + threadIdx.x;
  if (i < n) dinv[i] = rsqrtf(1.0f + (float)(rowptr[i + 1] - rowptr[i]));
}

__global__ __launch_bounds__(256) void bucket(const int* __restrict__ src, const int* __restrict__ dst,
                                              int* __restrict__ cur, int* __restrict__ ssrc, int e) {
  int i = blockIdx.x * 256 + threadIdx.x;
  if (i < e) ssrc[atomicAdd(&cur[dst[i]], 1)] = src[i];
}

// gstart[g] = first node index of graph g (batch sorted); gstart[G] = N
__global__ __launch_bounds__(256) void graph_starts(const int* __restrict__ batch,
                                                    int* __restrict__ gstart, int n) {
  int i = blockIdx.x * 256 + threadIdx.x;
  if (i < n) {
    int b = batch[i];
    int bp = (i == 0) ? -1 : batch[i - 1];
    for (int g = bp + 1; g <= b; ++g) gstart[g] = i;
  } else if (i == n) {
    int bl = batch[n - 1];
    for (int g = bl + 1; g <= N_GRAPHS; ++g) gstart[g] = n;
  }
}

// MFMA GEMM: out[M, Nout] = f16(in[M, K(pad KP)]) @ f16(W[:, coff..]) + epilogue
// OUT_MODE 0: v*=rs[row] -> f16 outp (stride LDO)
// OUT_MODE 1: relu(v+bo[oc]) -> f16 outp ; OUT_MODE 2: v+bo[oc] -> f32 outp
template <typename TIN, int OUT_MODE>
__global__ __launch_bounds__(256) void gemm_mfma(
    const TIN* __restrict__ in, const float* __restrict__ W,
    void* __restrict__ outp, const float* __restrict__ rs, const float* __restrict__ bo,
    int M, int K, int KP, int Nout, int ldw, int coff, int LDO) {
  __shared__ _Float16 As[128][40];
  __shared__ _Float16 Bs[80][40];
  const int tid = threadIdx.x;
  const int lane = tid & 63;
  const int wid = tid >> 6;
  const int row0 = blockIdx.y * 128;
  const int col0 = blockIdx.x * 80;
  const f32x4 z4 = {0.f, 0.f, 0.f, 0.f};
  f32x4 acc[2][5];
#pragma unroll
  for (int a = 0; a < 2; ++a)
#pragma unroll
    for (int b = 0; b < 5; ++b) acc[a][b] = z4;

  const int nsteps = (K + 31) >> 5;
  for (int s = 0; s < nsteps; ++s) {
    const int k0 = s << 5;
    if constexpr (sizeof(TIN) == 2) {
#pragma unroll
      for (int i = 0; i < 2; ++i) {
        int id = tid + i * 256;
        int r = id >> 2, kc = (id & 3) << 3;
        int gr = row0 + r, gk = k0 + kc;
        uint4 v = {0u, 0u, 0u, 0u};
        if (gr < M && gk + 8 <= KP)
          v = *reinterpret_cast<const uint4*>((const _Float16*)in + (size_t)gr * KP + gk);
        *reinterpret_cast<uint4*>(&As[r][kc]) = v;
      }
    } else {
#pragma unroll
      for (int i = 0; i < 8; ++i) {
        int id = tid + i * 256;
        int r = id >> 4, c2 = id & 15;
        int gr = row0 + r, gk = k0 + 2 * c2;
        __half2 h = __floats2half2_rn(0.f, 0.f);
        if (gr < M && gk + 2 <= KP) {
          float2 v = *reinterpret_cast<const float2*>((const float*)in + (size_t)gr * KP + gk);
          h = __floats2half2_rn(v.x, v.y);
        }
        *reinterpret_cast<__half2*>(&As[r][2 * c2]) = h;
      }
    }
#pragma unroll
    for (int i = 0; i < 10; ++i) {
      int id = tid + i * 256;
      int k = id / 80, c = id - k * 80;
      float v = 0.f;
      if (k0 + k < K && col0 + c < Nout)
        v = W[(size_t)(k0 + k) * ldw + coff + col0 + c];
      Bs[c][k] = (_Float16)v;
    }
    __syncthreads();
    f16x8 af[2], bf[5];
#pragma unroll
    for (int rf = 0; rf < 2; ++rf)
      af[rf] = *reinterpret_cast<const f16x8*>(&As[wid * 32 + rf * 16 + (lane & 15)][(lane >> 4) * 8]);
#pragma unroll
    for (int nf = 0; nf < 5; ++nf)
      bf[nf] = *reinterpret_cast<const f16x8*>(&Bs[nf * 16 + (lane & 15)][(lane >> 4) * 8]);
#pragma unroll
    for (int rf = 0; rf < 2; ++rf)
#pragma unroll
      for (int nf = 0; nf < 5; ++nf)
        acc[rf][nf] = __builtin_amdgcn_mfma_f32_16x16x32_f16(af[rf], bf[nf], acc[rf][nf], 0, 0, 0);
    __syncthreads();
  }

#pragma unroll
  for (int rf = 0; rf < 2; ++rf) {
#pragma unroll
    for (int j = 0; j < 4; ++j) {
      int gr = row0 + wid * 32 + rf * 16 + (lane >> 4) * 4 + j;
      if (gr >= M) continue;
      float sc = (OUT_MODE == 0) ? rs[gr] : 0.f;
#pragma unroll
      for (int nf = 0; nf < 5; ++nf) {
        int oc = col0 + nf * 16 + (lane & 15);
        if (oc >= Nout) continue;
        float v = acc[rf][nf][j];
        if (OUT_MODE == 0) {
          ((_Float16*)outp)[(size_t)gr * LDO + oc] = (_Float16)(v * sc);
        } else if (OUT_MODE == 1) {
          ((_Float16*)outp)[(size_t)gr * LDO + oc] = (_Float16)fmaxf(v + bo[oc], 0.f);
        } else {
          ((float*)outp)[(size_t)gr * LDO + oc] = v + bo[oc];
        }
      }
    }
  }
}

// Fused segment-sum + transform (layers 1-2). hs stride 80 fp16.
// dsth[n, coff+c] = fp16(relu(dinv[n]*(hs[n]+Σ_seg hs[ssrc]) + b[coff+c]))
__global__ __launch_bounds__(256) void aggregate78(
    const _Float16* __restrict__ hs, const int* __restrict__ rowptr,
    const int* __restrict__ ssrc, const float* __restrict__ dinv,
    const float* __restrict__ b, _Float16* __restrict__ dsth, int ldo, int coff) {
  unsigned idx = blockIdx.x * 256u + threadIdx.x;
  if (idx >= (unsigned)N_NODES * 39u) return;
  unsigned n = idx / 39u, c = idx - n * 39u;
  const unsigned co = 2u * c;
  __half2 h0 = *reinterpret_cast<const __half2*>(hs + (size_t)n * 80 + co);
  float ax = __half2float(h0.x), ay = __half2float(h0.y);
  int s0 = rowptr[n], s1 = rowptr[n + 1];
  for (int i = s0; i < s1; ++i) {
    int s = ssrc[i];
    __half2 v = *reinterpret_cast<const __half2*>(hs + (size_t)s * 80 + co);
    ax += __half2float(v.x);
    ay += __half2float(v.y);
  }
  float di = dinv[n];
  float r0 = fmaxf(fmaf(di, ax, b[coff + co]), 0.f);
  float r1 = fmaxf(fmaf(di, ay, b[coff + co + 1]), 0.f);
  *reinterpret_cast<__half2*>(dsth + (size_t)n * ldo + coff + co) = __floats2half2_rn(r0, r1);
}

// Layer-3 pool: one wave per graph, no atomics.
// GA[g, coff+c] = fp16( (1/cnt) * Σ_{n in graph} relu(dinv[n]*agg[n,c] + b3[coff+c]) )
template <int LAST>
__global__ __launch_bounds__(256) void pool_graph(
    const _Float16* __restrict__ hs, const int* __restrict__ rowptr,
    const int* __restrict__ ssrc, const float* __restrict__ dinv,
    const float* __restrict__ b3, const int* __restrict__ gstart,
    _Float16* __restrict__ GA, int coff) {
  const int w = threadIdx.x >> 6, lane = threadIdx.x & 63;
  const int g = blockIdx.x * 4 + w;
  if (g >= N_GRAPHS) return;
  const int n0 = gstart[g], n1 = gstart[g + 1];
  if (lane < 39) {
    const int co = 2 * lane;
    const float bx = b3[coff + co], by = b3[coff + co + 1];
    float accx = 0.f, accy = 0.f;
    for (int n = n0; n < n1; ++n) {
      __half2 h = *reinterpret_cast<const __half2*>(hs + (size_t)n * 80 + co);
      float ax = __half2float(h.x), ay = __half2float(h.y);
      int e0 = rowptr[n], e1 = rowptr[n + 1];
      for (int i = e0; i < e1; ++i) {
        int s = ssrc[i];
        __half2 v = *reinterpret_cast<const __half2*>(hs + (size_t)s * 80 + co);
        ax += __half2float(v.x);
        ay += __half2float(v.y);
      }
      float di = dinv[n];
      accx += fmaxf(fmaf(di, ax, bx), 0.f);
      accy += fmaxf(fmaf(di, ay, by), 0.f);
    }
    float gi = 1.0f / fmaxf((float)(n1 - n0), 1.0f);
    *reinterpret_cast<__half2*>(GA + (size_t)g * 320 + coff + co) =
        __floats2half2_rn(accx * gi, accy * gi);
  } else if (LAST && lane < 43) {
    *reinterpret_cast<__half2*>(GA + (size_t)g * 320 + 312 + 2 * (lane - 39)) =
        __floats2half2_rn(0.f, 0.f);
  }
}

extern "C" void kernel_launch(void* const* d_in, const int* in_sizes, int n_in,
                              void* d_out, int out_size, void* d_ws, size_t ws_size,
                              hipStream_t stream) {
  const float* x   = (const float*)d_in[0];
  const int* ei    = (const int*)d_in[1];
  const int* batch = (const int*)d_in[2];
  const float* W1 = (const float*)d_in[3];
  const float* b1 = (const float*)d_in[4];
  const float* W2 = (const float*)d_in[5];
  const float* b2 = (const float*)d_in[6];
  const float* W3 = (const float*)d_in[7];
  const float* b3 = (const float*)d_in[8];
  const float* fW1 = (const float*)d_in[9];
  const float* fb1 = (const float*)d_in[10];
  const float* fW2 = (const float*)d_in[11];
  const float* fb2 = (const float*)d_in[12];
  float* out = (float*)d_out;

  const int Nn = N_NODES, E = N_EDGES, G = N_GRAPHS;
  const int* src = ei;
  const int* dst = ei + E;

  // ---- workspace layout (~386 MB) ----
  _Float16* HSh   = (_Float16*)d_ws;                      // [N,80]  hs chunk
  _Float16* AGG1h = HSh + (size_t)Nn * 80;                // [N,80]  L2 input
  _Float16* AGG2h = AGG1h + (size_t)Nn * 80;              // [N,160] L3 input
  float* dinv     = (float*)(AGG2h + (size_t)Nn * 160);   // [N]
  int* rowptr     = (int*)(dinv + Nn);                    // [N+1]
  int* cur        = rowptr + Nn + 1;                      // [N]
  int* ssrc       = cur + Nn;                             // [E]
  int* partials   = ssrc + E;                             // [512]
  int* gstart     = partials + 512;                       // [G+1]
  _Float16* GA    = (_Float16*)(gstart + G + 1);          // [G,320]
  _Float16* fc1   = GA + (size_t)G * 320;                 // [G,1024]

  dim3 blk(256);
  const int gN39 = (int)(((unsigned)Nn * 39u + 255u) / 256u);
  const dim3 nodeGrid(1, (Nn + 127) / 128);
  const int NB = (Nn + 1023) / 1024;  // 489
  const int poolGrid = (G + 3) / 4;   // 4 graphs (waves) per block

  // ---- CSR build (dst-sorted src list) ----
  fill_u32<<<(Nn + 255) / 256, blk, 0, stream>>>((unsigned*)cur, 0u, Nn);
  hist_dst<<<(E + 255) / 256, blk, 0, stream>>>(dst, cur, E);
  scanA<<<NB, blk, 0, stream>>>(cur, rowptr, partials, Nn);
  scanB<<<1, 512, 0, stream>>>(partials, NB);
  scanC<<<(Nn + 255) / 256, blk, 0, stream>>>(rowptr, partials, cur, Nn, E);
  dinv_k<<<(Nn + 255) / 256, blk, 0, stream>>>(rowptr, dinv, Nn);
  bucket<<<(E + 255) / 256, blk, 0, stream>>>(src, dst, cur, ssrc, E);
  graph_starts<<<(Nn + 256) / 256, blk, 0, stream>>>(batch, gstart, Nn);

  // ---- zero fp16 pad columns (ws poisoned 0xAA once) ----
  pad_zero_u32<<<(Nn + 255) / 256, blk, 0, stream>>>((unsigned*)HSh, 40, 39, 1, Nn);
  pad_zero_u32<<<(Nn + 255) / 256, blk, 0, stream>>>((unsigned*)AGG1h, 40, 39, 1, Nn);
  pad_zero_u32<<<(2 * Nn + 255) / 256, blk, 0, stream>>>((unsigned*)AGG2h, 80, 78, 2, Nn);

  // ---- layer 1 ----
  gemm_mfma<float, 0><<<nodeGrid, blk, 0, stream>>>(
      x, W1, HSh, dinv, nullptr, Nn, 78, 78, 78, 78, 0, 80);
  aggregate78<<<gN39, blk, 0, stream>>>(HSh, rowptr, ssrc, dinv, b1, AGG1h, 80, 0);

  // ---- layer 2 (2 chunks of 78) ----
  for (int c = 0; c < 2; ++c) {
    gemm_mfma<_Float16, 0><<<nodeGrid, blk, 0, stream>>>(
        AGG1h, W2, HSh, dinv, nullptr, Nn, 78, 80, 78, 156, 78 * c, 80);
    aggregate78<<<gN39, blk, 0, stream>>>(HSh, rowptr, ssrc, dinv, b2, AGG2h, 160, 78 * c);
  }

  // ---- layer 3 (4 chunks of 78) + per-graph register pool (no atomics) ----
  for (int c = 0; c < 4; ++c) {
    gemm_mfma<_Float16, 0><<<nodeGrid, blk, 0, stream>>>(
        AGG2h, W3, HSh, dinv, nullptr, Nn, 156, 160, 78, 312, 78 * c, 80);
    if (c == 3)
      pool_graph<1><<<poolGrid, blk, 0, stream>>>(HSh, rowptr, ssrc, dinv, b3, gstart, GA, 78 * c);
    else
      pool_graph<0><<<poolGrid, blk, 0, stream>>>(HSh, rowptr, ssrc, dinv, b3, gstart, GA, 78 * c);
  }

  // ---- FC1: relu(GA @ fW1 + fb1) -> fc1 f16 ----
  {
    dim3 g((1024 + 79) / 80, (G + 127) / 128);
    gemm_mfma<_Float16, 1><<<g, blk, 0, stream>>>(
        GA, fW1, fc1, nullptr, fb1, G, 312, 320, 1024, 1024, 0, 1024);
  }
  // ---- FC2: out = fc1 @ fW2 + fb2 ----
  {
    dim3 g((128 + 79) / 80, (G + 127) / 128);
    gemm_mfma<_Float16, 2><<<g, blk, 0, stream>>>(
        fc1, fW2, out, nullptr, fb2, G, 1024, 1024, 128, 128, 0, 128);
  }
}